// Round 22
// baseline (232.295 us; speedup 1.0000x reference)
//
#include <hip/hip_runtime.h>
#include <stdint.h>

#pragma clang fp contract(off)

typedef unsigned int u32;
typedef unsigned long long u64;
typedef unsigned char u8;

#define A_TOTAL 242991
#define KTOT    4741

// level tables
__constant__ int c_LN[5]   = {182400, 45600, 11400, 2850, 741};
__constant__ int c_LOFF[5] = {0, 182400, 228000, 239400, 242250};
__constant__ int c_LK[5]   = {1000, 1000, 1000, 1000, 741};

// scan segment tables: 33 segments/image of <=8192 elements (23 l0, 6 l1, 2 l2, 1 l3, 1 l4)
__constant__ int c_SL[33] = {0,0,0,0,0,0,0,0,0,0,0,0,0,0,0,0,0,0,0,0,0,0,0,
                             1,1,1,1,1,1, 2,2, 3, 4};
__constant__ int c_SS[33] = {0,8192,16384,24576,32768,40960,49152,57344,65536,
                             73728,81920,90112,98304,106496,114688,122880,131072,
                             139264,147456,155648,163840,172032,180224,
                             0,8192,16384,24576,32768,40960, 0,8192, 0, 0};

// workspace byte offsets (total ~8.73 MB)
// keepw ALIASES the hist region: hist is dead after k_collect; k_sdmn (writer)
// runs strictly before k_rank (reader).
static const size_t OFF_KEEPW    = 0;
static const size_t OFF_HIST     = 0;        // 40*2048*4 = 327680
static const size_t OFF_SELCNT   = 327680;   // 40*4
static const size_t OFF_CANDCNT  = 327840;   // 40*4
// zero-init region: [0, 328000) = 82000 u32 words (hist + selcnt + candcnt)
static const size_t OFF_SELG     = 328320;   // 40*1024*8  -> 656000
static const size_t OFF_CANDG    = 656000;   // 40*4096*8  -> 1966720
static const size_t OFF_BOX      = 2270144;  // 8*4741*4*4 -> 2876992
static const size_t OFF_OUTK     = 8423296;  // 8*4741*8   -> 8726720

// monotone float<->uint map: fmap ascending in float value
__device__ __forceinline__ u32 fmap(float f){
  u32 b = __float_as_uint(f);
  return (b & 0x80000000u) ? ~b : (b | 0x80000000u);
}
__device__ __forceinline__ float funmap(u32 m){
  return __uint_as_float((m & 0x80000000u) ? (m & 0x7FFFFFFFu) : ~m);
}

// ---------- K0: zero-init of hist + selcnt + candcnt ----------
#define ZWS 82000
__global__ void __launch_bounds__(256)
k_zero(u32* __restrict__ ws0)
{
  int i = blockIdx.x * 256 + (int)threadIdx.x;
  if (i < ZWS) ws0[i] = 0u;
}

// ---------- K1a: per-(b,l) 2048-bin histogram, float4 + 4-way privatized ----------
__global__ void __launch_bounds__(1024)
k_hist(const float* __restrict__ obj, u32* __restrict__ hist)
{
  int b = blockIdx.x / 33, s = blockIdx.x % 33;
  int l = c_SL[s], start = c_SS[s];
  int cnt = c_LN[l] - start; if (cnt > 8192) cnt = 8192;
  int bl = b * 5 + l;
  __shared__ u32 h[4][2048];   // 32 KiB
  for (int i = threadIdx.x; i < 8192; i += 1024) ((u32*)h)[i] = 0;
  __syncthreads();
  u32* hw = h[(threadIdx.x >> 6) & 3];
  const float* p = obj + (size_t)b * A_TOTAL + c_LOFF[l] + start;
  int head = (4 - (int)(((size_t)p >> 2) & 3)) & 3;
  if (head > cnt) head = cnt;
  if ((int)threadIdx.x < head) atomicAdd(&hw[(~fmap(p[threadIdx.x])) >> 21], 1u);
  int nvec = (cnt - head) >> 2;
  const float4* pv = (const float4*)(p + head);
  for (int i = threadIdx.x; i < nvec; i += 1024){
    float4 v = pv[i];
    atomicAdd(&hw[(~fmap(v.x)) >> 21], 1u);
    atomicAdd(&hw[(~fmap(v.y)) >> 21], 1u);
    atomicAdd(&hw[(~fmap(v.z)) >> 21], 1u);
    atomicAdd(&hw[(~fmap(v.w)) >> 21], 1u);
  }
  int tail0 = head + (nvec << 2);
  int ntail = cnt - tail0;
  if ((int)threadIdx.x < ntail) atomicAdd(&hw[(~fmap(p[tail0 + threadIdx.x])) >> 21], 1u);
  __syncthreads();
  for (int i = threadIdx.x; i < 2048; i += 1024){
    u32 v = h[0][i] + h[1][i] + h[2][i] + h[3][i];
    if (v) atomicAdd(&hist[bl * 2048 + i], v);
  }
}

// ---------- K1c: collect with INLINE cutoff (as in R21, measured good) ----------
#define SELCAP 2048
#define CANDCAP 1024
__global__ void __launch_bounds__(1024)
k_collect(const float* __restrict__ obj, const u32* __restrict__ hist,
          u32* __restrict__ selcnt, u32* __restrict__ candcnt,
          u64* __restrict__ selg, u64* __restrict__ candg)
{
  int b = blockIdx.x / 33, s = blockIdx.x % 33;
  int l = c_SL[s], start = c_SS[s];
  int cnt = c_LN[l] - start; if (cnt > 8192) cnt = 8192;
  int bl = b * 5 + l;
  int K = c_LK[l], n = c_LN[l];
  int tid = threadIdx.x;
  __shared__ u64 lsel[SELCAP];    // 16 KiB
  __shared__ u64 lcand[CANDCAP];  //  8 KiB
  __shared__ u32 part[1024];      //  4 KiB
  __shared__ u32 lcs, lcc, gbs, gbc, s_tval;
  if (tid == 0){ lcs = 0u; lcc = 0u; }
  // ---- inline cutoff (2-level wave scan; t bit-identical to old k_cutoff) ----
  if (K < n) part[tid] = hist[bl * 2048 + 2 * tid] + hist[bl * 2048 + 2 * tid + 1];
  __syncthreads();
  if (K < n && tid < 64){
    u32 gs = 0;
    #pragma unroll
    for (int q = 0; q < 16; ++q) gs += part[tid * 16 + q];   // 32-bin group sum
    u32 c = gs;
    for (int off = 1; off < 64; off <<= 1){
      u32 u = __shfl_up(c, off);
      if (tid >= off) c += u;
    }
    u32 cp = c - gs;
    bool crossing = (c >= (u32)K) && (cp < (u32)K);
    u64 bal = __ballot(crossing);
    int jj = __ffsll((unsigned long long)bal) - 1;
    u32 cpj = (u32)__shfl((int)cp, jj);
    u32 bv = (tid < 32) ? hist[bl * 2048 + jj * 32 + tid] : 0u;
    u32 cb = bv;
    for (int off2 = 1; off2 < 32; off2 <<= 1){
      u32 u2 = __shfl_up(cb, off2);
      if ((int)(tid & 31) >= off2) cb += u2;
    }
    bool cross2 = (tid < 32) && (cpj + cb >= (u32)K) && (cpj + cb - bv < (u32)K);
    u64 bal2 = __ballot(cross2);
    int kk = __ffsll((unsigned long long)bal2) - 1;
    if (tid == 0) s_tval = (u32)(jj * 32 + kk);
  }
  __syncthreads();
  u32 t = (K >= n) ? 2048u : s_tval;
  const float* p = obj + (size_t)b * A_TOTAL + c_LOFF[l] + start;

  auto push = [&](u32 m, int idx){
    u32 bin = m >> 21;
    u64 key = ((u64)m << 32) | (u32)idx;
    if (bin < t){
      u32 pos = atomicAdd(&lcs, 1u);
      if (pos < SELCAP) lsel[pos] = key;
      else { u32 gp = atomicAdd(&selcnt[bl], 1u); selg[(size_t)bl * 1024 + gp] = key; }
    } else if (bin == t){
      u32 pos = atomicAdd(&lcc, 1u);
      if (pos < CANDCAP) lcand[pos] = key;
      else { u32 gp = atomicAdd(&candcnt[bl], 1u); if (gp < 4096u) candg[(size_t)bl * 4096 + gp] = key; }
    }
  };

  int head = (4 - (int)(((size_t)p >> 2) & 3)) & 3;
  if (head > cnt) head = cnt;
  if (tid < head) push(~fmap(p[tid]), start + tid);
  int nvec = (cnt - head) >> 2;
  const float4* pv = (const float4*)(p + head);
  for (int i = tid; i < nvec; i += 1024){
    float4 v = pv[i];
    int e = start + head + (i << 2);
    push(~fmap(v.x), e);
    push(~fmap(v.y), e + 1);
    push(~fmap(v.z), e + 2);
    push(~fmap(v.w), e + 3);
  }
  int tail0 = head + (nvec << 2);
  int ntail = cnt - tail0;
  if (tid < ntail) push(~fmap(p[tail0 + tid]), start + tail0 + tid);
  __syncthreads();
  u32 ns = lcs;  if (ns > SELCAP) ns = SELCAP;
  u32 ncd = lcc; if (ncd > CANDCAP) ncd = CANDCAP;
  if (tid == 0){
    gbs = ns  ? atomicAdd(&selcnt[bl],  ns)  : 0u;
    gbc = ncd ? atomicAdd(&candcnt[bl], ncd) : 0u;
  }
  __syncthreads();
  u32 bs = gbs, bc = gbc;
  for (u32 i = tid; i < ns; i += 1024)
    selg[(size_t)bl * 1024 + bs + i] = lsel[i];
  for (u32 i = tid; i < ncd; i += 1024){
    u32 gp = bc + i;
    if (gp < 4096u) candg[(size_t)bl * 4096 + gp] = lcand[i];
  }
}

// ---------- K2: FUSED select+decode+mask+NMS, one block per (b,level) ----------
// Phase 1: rank sel/cand keys (flat counting-rank) -> keysL.
// Phase 2: decode -> boxes global (for k_rank) + offset boxes/areas/scores/valid in LDS.
// Phase 3: full suppression mask into LDS buf (overlays dead selU/candU):
//          word w at base 32*w*(w+1), rows < min(N,(w+1)*64)  (8680 u64 max).
// Phase 4: exact greedy scan (wave 0) with sparse-conflict fast path.
// Phase 5: emit outk keys + keepw; also zeroes this block's d_out slice.
// The mask/scores/valid never touch global memory.
__global__ void __launch_bounds__(1024)
k_sdmn(const u32* __restrict__ selcnt, const u32* __restrict__ candcnt,
       const u64* __restrict__ selg, const u64* __restrict__ candg,
       const float* __restrict__ deltas, const float* __restrict__ anchors,
       float* __restrict__ boxes, u64* __restrict__ outk,
       u64* __restrict__ keepw, float* __restrict__ outz)
{
  int bl = blockIdx.x; int b = bl / 5, l = bl % 5;
  int K = c_LK[l];
  int N = K;                         // kout rows = K = level's N
  int koff = l * 1000;
  int WN = (N + 63) >> 6;
  int tid = threadIdx.x;
  __shared__ __align__(16) u64 buf[8704];   // 68 KiB: selU/candU, then s_m
  __shared__ u64 keysL[1000];               //  8 KiB
  __shared__ float bx1L[1024], by1L[1024], bx2L[1024], by2L[1024], arL[1024], scoresL[1024]; // 24 KiB
  __shared__ u8  validB[1024];              //  1 KiB
  __shared__ u64 s_kw[16];
  u64* selU  = buf;                  // 1024 slots
  u64* candU = buf + 1024;           // 4098+ slots
  // zero this block's 1000-float slice of d_out (completes before k_rank)
  for (int i = tid; i < 1000; i += 256) if (tid < 256) outz[bl * 1000 + i] = 0.0f;
  for (int i = tid; i < 1000; i += 1024) outz[bl * 1000 + i] = 0.0f;  // all waves (redundant-safe)
  u32 ns = selcnt[bl]; if (ns > 1024u) ns = 1024u;
  u32 nc = candcnt[bl]; if (nc > 4096u) nc = 4096u;
  int R = K - (int)ns;
  selU[tid] = (tid < (int)ns) ? selg[(size_t)bl * 1024 + tid] : ~0ULL;
  for (u32 i = tid; i < nc; i += 1024) candU[i] = candg[(size_t)bl * 4096 + i];
  u32 nce = (nc + 1u) & ~1u;
  if (tid == 0 && nce > nc) candU[nc] = ~0ULL;
  __syncthreads();
  // Phase 1: counting rank
  u64 mykey = (tid < (int)ns) ? selU[tid] : ~0ULL;
  if (tid < (int)ns){
    u32 r = 0;
    #pragma unroll 8
    for (u32 j = 0; j < 1024; j += 2){
      ulonglong2 v = *reinterpret_cast<const ulonglong2*>(&selU[j]);
      r += (v.x < mykey) + (v.y < mykey);
    }
    keysL[r] = mykey;
  }
  if (R > 0){
    for (u32 s = tid; s < nc; s += 1024){
      u64 key = candU[s];
      u32 r = 0;
      #pragma unroll 8
      for (u32 j = 0; j < nce; j += 2){
        ulonglong2 v = *reinterpret_cast<const ulonglong2*>(&candU[j]);
        r += (v.x < key) + (v.y < key);
      }
      if (r < (u32)R) keysL[ns + r] = key;
    }
  }
  __syncthreads();
  // Phase 2: decode; boxes -> global + offset boxes/areas/scores/valid -> LDS
  float offv = (float)(l * 4096);   // exact
  if (tid < K){
    u64 key = keysL[tid];
    int g = b * KTOT + koff + tid;
    u32 idx = (u32)key;
    float o = funmap(~(u32)(key >> 32));
    int ai = c_LOFF[l] + (int)idx;
    const float* a = anchors + (size_t)ai * 4;
    const float* d = deltas + ((size_t)b * A_TOTAL + ai) * 4;
    float a0 = a[0], a1 = a[1], a2 = a[2], a3 = a[3];
    float wa = __fsub_rn(a2, a0), ha = __fsub_rn(a3, a1);
    float cxa = __fadd_rn(a0, __fmul_rn(0.5f, wa));
    float cya = __fadd_rn(a1, __fmul_rn(0.5f, ha));
    float dx = d[0], dy = d[1];
    float dw = fminf(d[2], 4.135166556742356f);   // log(1000/16)
    float dh = fminf(d[3], 4.135166556742356f);
    float cx = __fadd_rn(__fmul_rn(dx, wa), cxa);
    float cy = __fadd_rn(__fmul_rn(dy, ha), cya);
    float w  = __fmul_rn(expf(dw), wa);
    float h  = __fmul_rn(expf(dh), ha);
    float hw = __fmul_rn(0.5f, w), hh = __fmul_rn(0.5f, h);
    float x1 = __fsub_rn(cx, hw), y1 = __fsub_rn(cy, hh);
    float x2 = __fadd_rn(cx, hw), y2 = __fadd_rn(cy, hh);
    x1 = fminf(fmaxf(x1, 0.0f), 1216.0f);
    x2 = fminf(fmaxf(x2, 0.0f), 1216.0f);
    y1 = fminf(fmaxf(y1, 0.0f), 800.0f);
    y2 = fminf(fmaxf(y2, 0.0f), 800.0f);
    float sc = __fdiv_rn(1.0f, __fadd_rn(1.0f, expf(-o)));
    int v = (__fsub_rn(x2, x1) >= 0.001f) && (__fsub_rn(y2, y1) >= 0.001f) && (sc >= 0.0f);
    float* bo = boxes + (size_t)g * 4;
    bo[0] = x1; bo[1] = y1; bo[2] = x2; bo[3] = y2;
    float ox1 = __fadd_rn(x1, offv), oy1 = __fadd_rn(y1, offv);
    float ox2 = __fadd_rn(x2, offv), oy2 = __fadd_rn(y2, offv);
    bx1L[tid] = ox1; by1L[tid] = oy1; bx2L[tid] = ox2; by2L[tid] = oy2;
    arL[tid] = __fmul_rn(__fsub_rn(ox2, ox1), __fsub_rn(oy2, oy1));
    scoresL[tid] = sc;
    validB[tid] = (u8)v;
  } else {
    // sentinel: empty far-away box -> inter = 0 -> never suppresses
    bx1L[tid] = 3e38f; by1L[tid] = 3e38f; bx2L[tid] = -3e38f; by2L[tid] = -3e38f;
    arL[tid] = 0.f; scoresL[tid] = 0.f; validB[tid] = 0;
  }
  __syncthreads();
  // Phase 3: suppression mask into buf (overlays dead selU/candU)
  u64* s_m = buf;
  for (int w = 0; w < WN; ++w){
    int rowsw = (w + 1) * 64; if (rowsw > N) rowsw = N;
    int base = 32 * w * (w + 1);
    int jbase = w * 64;
    for (int i = tid; i < rowsw; i += 1024){
      float bx1 = bx1L[i], by1 = by1L[i], bx2 = bx2L[i], by2 = by2L[i], bar = arL[i];
      u64 bw = 0;
      #pragma unroll 16
      for (int jj = 0; jj < 64; ++jj){
        int j = jbase + jj;
        float ltx = fmaxf(bx1, bx1L[j]), lty = fmaxf(by1, by1L[j]);
        float rbx = fminf(bx2, bx2L[j]), rby = fminf(by2, by2L[j]);
        float wx = fmaxf(__fsub_rn(rbx, ltx), 0.0f);
        float wy = fmaxf(__fsub_rn(rby, lty), 0.0f);
        float inter = __fmul_rn(wx, wy);
        bool sup = false;
        if (inter > 0.0f && j > i){
          float den = __fsub_rn(__fadd_rn(bar, arL[j]), inter);
          sup = __fdiv_rn(inter, den) > 0.7f;
        }
        bw |= ((u64)sup) << jj;
      }
      s_m[base + i] = bw;
    }
  }
  __syncthreads();
  // Phase 4: exact greedy scan (wave 0), sparse-conflict fast path
  if (tid < 64){
    int lane = tid;
    for (int c = 0; c < WN; ++c){
      int i = c * 64 + lane;
      int pred = (i < N) && (validB[i] != 0);
      u64 bal = __ballot(pred);
      if (lane == 0) s_kw[c] = bal;
    }
    for (int w = 0; w < WN; ++w){
      u64 kwv = s_kw[w];
      int base = 32 * w * (w + 1);
      u64 supl = 0;
      for (int jb = 0; jb < w; ++jb){
        u64 kb = s_kw[jb];
        u64 m = s_m[base + jb * 64 + lane];
        supl |= (((kb >> lane) & 1ULL) ? m : 0ULL);
      }
      int jr = w * 64 + lane;
      u64 rowl = (jr < N) ? s_m[base + jr] : 0ULL;
      bool inC = ((kwv >> lane) & 1ULL) != 0ULL;
      u64 rkw = rowl & kwv;
      u64 confl = inC ? rkw : 0ULL;
      u32 a0 = (u32)supl, a1 = (u32)(supl >> 32);
      u32 a2 = (u32)confl, a3 = (u32)(confl >> 32);
      for (int off = 32; off; off >>= 1){
        a0 |= __shfl_xor(a0, off);
        a1 |= __shfl_xor(a1, off);
        a2 |= __shfl_xor(a2, off);
        a3 |= __shfl_xor(a3, off);
      }
      supl = ((u64)a1 << 32) | a0;
      u64 conf = ((u64)a3 << 32) | a2;
      u64 srcb = __ballot(inC && (rkw != 0ULL));
      u64 cur = kwv & ~supl;
      u64 kept = cur;
      if (((srcb & cur) != 0ULL) && ((conf & cur) != 0ULL)){
        u32 rowl_lo = (u32)rowl, rowl_hi = (u32)(rowl >> 32);
        u64 act = cur & (srcb | conf);
        while (act){
          int ib  = __ffsll((unsigned long long)act) - 1;
          int ibs = __builtin_amdgcn_readfirstlane(ib);
          u64 bit = 1ULL << ibs;
          act &= ~bit;
          if (kept & bit){
            u32 rlo = (u32)__builtin_amdgcn_readlane((int)rowl_lo, ibs);
            u32 rhi = (u32)__builtin_amdgcn_readlane((int)rowl_hi, ibs);
            u64 r   = ((u64)rhi << 32) | rlo;
            kept &= ~r;
            act  &= ~r;
          }
        }
      }
      if (lane == 0) s_kw[w] = kept;
    }
  }
  __syncthreads();
  // Phase 5: export keepw + emit outk keys (scores from LDS)
  if (tid < 16) keepw[(size_t)bl * 16 + tid] = (tid < WN) ? s_kw[tid] : 0ULL;
  for (int i = tid; i < N; i += 1024){
    u64 key = ~0ULL;
    if ((s_kw[i >> 6] >> (i & 63)) & 1ULL){
      float sc = scoresL[i];
      key = ((u64)(~fmap(sc)) << 32) | (u32)(koff + i);
    }
    outk[(size_t)b * KTOT + koff + i] = key;
  }
}

// ---------- K5: 5-way merge-rank final selection (O(K log K)) ----------
#define CMPN 1024   // per-level compacted list, padded with ~0ULL (kept count <= 1000)
__global__ void __launch_bounds__(256)
k_rank(const u64* __restrict__ outk, const u64* __restrict__ keepw,
       const float* __restrict__ boxes, float* __restrict__ out)
{
  int b = blockIdx.x / 19, chunk = blockIdx.x % 19;
  int tid = threadIdx.x;
  __shared__ u64 cmp[5 * CMPN];   // 40 KiB
  __shared__ u64 kw[80];          // keep words for this image's 5 levels
  for (int i = tid; i < 5 * CMPN; i += 256) cmp[i] = ~0ULL;
  if (tid < 80) kw[tid] = keepw[(size_t)b * 80 + tid];
  __syncthreads();
  for (int i = tid; i < KTOT; i += 256){
    u64 key = outk[(size_t)b * KTOT + i];
    if (key != ~0ULL){
      int l = i / 1000; if (l > 4) l = 4;
      int li = i - l * 1000;
      int wi = li >> 6, bit = li & 63;
      const u64* kwl = &kw[l * 16];
      int r = __popcll(kwl[wi] & ((1ULL << bit) - 1ULL));
      for (int w = 0; w < wi; ++w) r += __popcll(kwl[w]);
      cmp[l * CMPN + r] = key;
    }
  }
  __syncthreads();
  int i = chunk * 256 + tid;
  if (i >= KTOT) return;
  u64 key = outk[(size_t)b * KTOT + i];
  if (key == ~0ULL) return;     // suppressed / invalid
  int l = i / 1000; if (l > 4) l = 4;
  int li = i - l * 1000;
  int wi = li >> 6, bit = li & 63;
  const u64* kwl = &kw[l * 16];
  int rank = __popcll(kwl[wi] & ((1ULL << bit) - 1ULL));
  for (int w = 0; w < wi; ++w) rank += __popcll(kwl[w]);
  #pragma unroll
  for (int lo = 0; lo < 5; ++lo){
    if (lo == l) continue;
    int pos = 0;
    #pragma unroll
    for (int s = 512; s > 0; s >>= 1)
      if (cmp[lo * CMPN + pos + s - 1] < key) pos += s;
    rank += pos;   // count of kept keys in level lo that are < key
  }
  if (rank < 1000){
    float4 bx = ((const float4*)boxes)[(size_t)(b * KTOT + i)];
    ((float4*)out)[(size_t)(b * 1000 + rank)] = bx;
    out[32000 + b * 1000 + rank] = funmap(~(u32)(key >> 32));
  }
}

extern "C" void kernel_launch(void* const* d_in, const int* in_sizes, int n_in,
                              void* d_out, int out_size, void* d_ws, size_t ws_size,
                              hipStream_t stream)
{
  (void)in_sizes; (void)n_in; (void)out_size; (void)ws_size; // needs ~8.73 MB ws
  const float* obj     = (const float*)d_in[0];
  const float* deltas  = (const float*)d_in[1];
  const float* anchors = (const float*)d_in[2];
  float* out = (float*)d_out;
  char* ws = (char*)d_ws;

  u32* hist    = (u32*)(ws + OFF_HIST);
  u64* keepw   = (u64*)(ws + OFF_KEEPW);   // aliases hist (dead by k_sdmn time)
  u32* selcnt  = (u32*)(ws + OFF_SELCNT);
  u32* candcnt = (u32*)(ws + OFF_CANDCNT);
  u64* selg    = (u64*)(ws + OFF_SELG);
  u64* candg   = (u64*)(ws + OFF_CANDG);
  float* boxes = (float*)(ws + OFF_BOX);
  u64* outk    = (u64*)(ws + OFF_OUTK);

  hipLaunchKernelGGL(k_zero,    dim3((ZWS + 255) / 256), dim3(256), 0, stream, (u32*)ws);
  hipLaunchKernelGGL(k_hist,    dim3(264), dim3(1024), 0, stream, obj, hist);
  hipLaunchKernelGGL(k_collect, dim3(264), dim3(1024), 0, stream, obj, hist, selcnt, candcnt, selg, candg);
  hipLaunchKernelGGL(k_sdmn,    dim3(40),  dim3(1024), 0, stream, selcnt, candcnt, selg, candg,
                     deltas, anchors, boxes, outk, keepw, out);
  hipLaunchKernelGGL(k_rank,    dim3(152), dim3(256),  0, stream, outk, keepw, boxes, out);
}

// Round 23
// 124.976 us; speedup vs baseline: 1.8587x; 1.8587x over previous
//
#include <hip/hip_runtime.h>
#include <stdint.h>

#pragma clang fp contract(off)

typedef unsigned int u32;
typedef unsigned long long u64;

#define A_TOTAL 242991
#define KTOT    4741

// level tables
__constant__ int c_LN[5]   = {182400, 45600, 11400, 2850, 741};
__constant__ int c_LOFF[5] = {0, 182400, 228000, 239400, 242250};
__constant__ int c_LK[5]   = {1000, 1000, 1000, 1000, 741};

// scan segment tables: 33 segments/image of <=8192 elements (23 l0, 6 l1, 2 l2, 1 l3, 1 l4)
__constant__ int c_SL[33] = {0,0,0,0,0,0,0,0,0,0,0,0,0,0,0,0,0,0,0,0,0,0,0,
                             1,1,1,1,1,1, 2,2, 3, 4};
__constant__ int c_SS[33] = {0,8192,16384,24576,32768,40960,49152,57344,65536,
                             73728,81920,90112,98304,106496,114688,122880,131072,
                             139264,147456,155648,163840,172032,180224,
                             0,8192,16384,24576,32768,40960, 0,8192, 0, 0};

// k_mask word-slab tables
__constant__ int c_MW[40] = {0,1,2,3, 4,4, 5,5, 6,6, 7,7, 8,8,8, 9,9,9,
                             10,10,10, 11,11,11, 12,12,12,12, 13,13,13,13,
                             14,14,14,14, 15,15,15,15};
__constant__ int c_MR[40] = {0,0,0,0, 0,1, 0,1, 0,1, 0,1, 0,1,2, 0,1,2,
                             0,1,2, 0,1,2, 0,1,2,3, 0,1,2,3,
                             0,1,2,3, 0,1,2,3};

// workspace byte offsets (total ~8.73 MB)
// keepw ALIASES the hist region: hist is dead after k_collect; k_nms (writer)
// runs strictly before k_rank (reader).
static const size_t OFF_KEEPW    = 0;
static const size_t OFF_HIST     = 0;        // 40*2048*4 = 327680
static const size_t OFF_SELCNT   = 327680;   // 40*4
static const size_t OFF_CANDCNT  = 327840;   // 40*4
// zero-init region: [0, 328000) = 82000 u32 words (hist + selcnt + candcnt)
static const size_t OFF_SELG     = 328320;   // 40*1024*8  -> 656000
static const size_t OFF_CANDG    = 656000;   // 40*4096*8  -> 1966720
static const size_t OFF_BOX      = 2270144;  // 8*4741*4*4 -> 2876992
static const size_t OFF_SCORE    = 2876992;  // 8*4741*4   -> 3028704
static const size_t OFF_VALID    = 3028704;  // 8*4741*4   -> 3180416
static const size_t OFF_MASK     = 3180416;  // 8*5*16*1024*8 -> 8423296
static const size_t OFF_OUTK     = 8423296;  // 8*4741*8   -> 8726720

// monotone float<->uint map: fmap ascending in float value
__device__ __forceinline__ u32 fmap(float f){
  u32 b = __float_as_uint(f);
  return (b & 0x80000000u) ? ~b : (b | 0x80000000u);
}
__device__ __forceinline__ float funmap(u32 m){
  return __uint_as_float((m & 0x80000000u) ? (m & 0x7FFFFFFFu) : ~m);
}

// ---------- K0: zero-init of hist + selcnt + candcnt ----------
#define ZWS 82000
__global__ void __launch_bounds__(256)
k_zero(u32* __restrict__ ws0)
{
  int i = blockIdx.x * 256 + (int)threadIdx.x;
  if (i < ZWS) ws0[i] = 0u;
}

// ---------- K1a: per-(b,l) 2048-bin histogram, float4 + 4-way privatized ----------
__global__ void __launch_bounds__(1024)
k_hist(const float* __restrict__ obj, u32* __restrict__ hist)
{
  int b = blockIdx.x / 33, s = blockIdx.x % 33;
  int l = c_SL[s], start = c_SS[s];
  int cnt = c_LN[l] - start; if (cnt > 8192) cnt = 8192;
  int bl = b * 5 + l;
  __shared__ u32 h[4][2048];   // 32 KiB
  for (int i = threadIdx.x; i < 8192; i += 1024) ((u32*)h)[i] = 0;
  __syncthreads();
  u32* hw = h[(threadIdx.x >> 6) & 3];
  const float* p = obj + (size_t)b * A_TOTAL + c_LOFF[l] + start;
  int head = (4 - (int)(((size_t)p >> 2) & 3)) & 3;
  if (head > cnt) head = cnt;
  if ((int)threadIdx.x < head) atomicAdd(&hw[(~fmap(p[threadIdx.x])) >> 21], 1u);
  int nvec = (cnt - head) >> 2;
  const float4* pv = (const float4*)(p + head);
  for (int i = threadIdx.x; i < nvec; i += 1024){
    float4 v = pv[i];
    atomicAdd(&hw[(~fmap(v.x)) >> 21], 1u);
    atomicAdd(&hw[(~fmap(v.y)) >> 21], 1u);
    atomicAdd(&hw[(~fmap(v.z)) >> 21], 1u);
    atomicAdd(&hw[(~fmap(v.w)) >> 21], 1u);
  }
  int tail0 = head + (nvec << 2);
  int ntail = cnt - tail0;
  if ((int)threadIdx.x < ntail) atomicAdd(&hw[(~fmap(p[tail0 + threadIdx.x])) >> 21], 1u);
  __syncthreads();
  for (int i = threadIdx.x; i < 2048; i += 1024){
    u32 v = h[0][i] + h[1][i] + h[2][i] + h[3][i];
    if (v) atomicAdd(&hist[bl * 2048 + i], v);
  }
}

// ---------- K1c: collect with INLINE cutoff (fused k_cutoff) ----------
#define SELCAP 2048
#define CANDCAP 1024
__global__ void __launch_bounds__(1024)
k_collect(const float* __restrict__ obj, const u32* __restrict__ hist,
          u32* __restrict__ selcnt, u32* __restrict__ candcnt,
          u64* __restrict__ selg, u64* __restrict__ candg)
{
  int b = blockIdx.x / 33, s = blockIdx.x % 33;
  int l = c_SL[s], start = c_SS[s];
  int cnt = c_LN[l] - start; if (cnt > 8192) cnt = 8192;
  int bl = b * 5 + l;
  int K = c_LK[l], n = c_LN[l];
  int tid = threadIdx.x;
  __shared__ u64 lsel[SELCAP];    // 16 KiB
  __shared__ u64 lcand[CANDCAP];  //  8 KiB
  __shared__ u32 part[1024];      //  4 KiB
  __shared__ u32 lcs, lcc, gbs, gbc, s_tval;
  if (tid == 0){ lcs = 0u; lcc = 0u; }
  // ---- inline cutoff ----
  if (K < n) part[tid] = hist[bl * 2048 + 2 * tid] + hist[bl * 2048 + 2 * tid + 1];
  __syncthreads();
  if (K < n && tid < 64){
    u32 gs = 0;
    #pragma unroll
    for (int q = 0; q < 16; ++q) gs += part[tid * 16 + q];   // 32-bin group sum
    u32 c = gs;
    for (int off = 1; off < 64; off <<= 1){
      u32 u = __shfl_up(c, off);
      if (tid >= off) c += u;
    }
    u32 cp = c - gs;                                          // cum before group
    bool crossing = (c >= (u32)K) && (cp < (u32)K);           // unique group
    u64 bal = __ballot(crossing);
    int jj = __ffsll((unsigned long long)bal) - 1;
    u32 cpj = (u32)__shfl((int)cp, jj);
    u32 bv = (tid < 32) ? hist[bl * 2048 + jj * 32 + tid] : 0u;
    u32 cb = bv;
    for (int off2 = 1; off2 < 32; off2 <<= 1){
      u32 u2 = __shfl_up(cb, off2);
      if ((int)(tid & 31) >= off2) cb += u2;
    }
    bool cross2 = (tid < 32) && (cpj + cb >= (u32)K) && (cpj + cb - bv < (u32)K);
    u64 bal2 = __ballot(cross2);
    int kk = __ffsll((unsigned long long)bal2) - 1;
    if (tid == 0) s_tval = (u32)(jj * 32 + kk);
  }
  __syncthreads();
  u32 t = (K >= n) ? 2048u : s_tval;
  // ---- collect ----
  const float* p = obj + (size_t)b * A_TOTAL + c_LOFF[l] + start;

  auto push = [&](u32 m, int idx){
    u32 bin = m >> 21;
    u64 key = ((u64)m << 32) | (u32)idx;
    if (bin < t){
      u32 pos = atomicAdd(&lcs, 1u);                       // LDS atomic
      if (pos < SELCAP) lsel[pos] = key;
      else { u32 gp = atomicAdd(&selcnt[bl], 1u); selg[(size_t)bl * 1024 + gp] = key; }
    } else if (bin == t){
      u32 pos = atomicAdd(&lcc, 1u);                       // LDS atomic
      if (pos < CANDCAP) lcand[pos] = key;
      else { u32 gp = atomicAdd(&candcnt[bl], 1u); if (gp < 4096u) candg[(size_t)bl * 4096 + gp] = key; }
    }
  };

  int head = (4 - (int)(((size_t)p >> 2) & 3)) & 3;
  if (head > cnt) head = cnt;
  if (tid < head) push(~fmap(p[tid]), start + tid);
  int nvec = (cnt - head) >> 2;
  const float4* pv = (const float4*)(p + head);
  for (int i = tid; i < nvec; i += 1024){
    float4 v = pv[i];
    int e = start + head + (i << 2);
    push(~fmap(v.x), e);
    push(~fmap(v.y), e + 1);
    push(~fmap(v.z), e + 2);
    push(~fmap(v.w), e + 3);
  }
  int tail0 = head + (nvec << 2);
  int ntail = cnt - tail0;
  if (tid < ntail) push(~fmap(p[tail0 + tid]), start + tail0 + tid);
  __syncthreads();
  u32 ns = lcs;  if (ns > SELCAP) ns = SELCAP;
  u32 ncd = lcc; if (ncd > CANDCAP) ncd = CANDCAP;
  if (tid == 0){
    gbs = ns  ? atomicAdd(&selcnt[bl],  ns)  : 0u;
    gbc = ncd ? atomicAdd(&candcnt[bl], ncd) : 0u;
  }
  __syncthreads();
  u32 bs = gbs, bc = gbc;
  for (u32 i = tid; i < ns; i += 1024)
    selg[(size_t)bl * 1024 + bs + i] = lsel[i];
  for (u32 i = tid; i < ncd; i += 1024){
    u32 gp = bc + i;
    if (gp < 4096u) candg[(size_t)bl * 4096 + gp] = lcand[i];
  }
}

// ---------- K1d: flat counting-rank top-K FUSED with decode ----------
__global__ void __launch_bounds__(1024)
k_selectdec(const u32* __restrict__ selcnt, const u32* __restrict__ candcnt,
            const u64* __restrict__ selg, const u64* __restrict__ candg,
            const float* __restrict__ deltas, const float* __restrict__ anchors,
            float* __restrict__ boxes, float* __restrict__ scores, u32* __restrict__ valid)
{
  int bl = blockIdx.x; int b = bl / 5, l = bl % 5;
  int K = c_LK[l];
  int tid = threadIdx.x;
  __shared__ __align__(16) u64 selU[1024];     //  8 KiB (padded with ~0)
  __shared__ __align__(16) u64 candU[4098];    // 32 KiB (+pad slot)
  __shared__ u64 keysL[1000];                  //  8 KiB
  u32 ns = selcnt[bl]; if (ns > 1024u) ns = 1024u;
  u32 nc = candcnt[bl]; if (nc > 4096u) nc = 4096u;
  int R = K - (int)ns;
  selU[tid] = (tid < (int)ns) ? selg[(size_t)bl * 1024 + tid] : ~0ULL;
  for (u32 i = tid; i < nc; i += 1024) candU[i] = candg[(size_t)bl * 4096 + i];
  u32 nce = (nc + 1u) & ~1u;
  if (tid == 0 && nce > nc) candU[nc] = ~0ULL;
  __syncthreads();
  // sel rank (fixed 512 broadcast ulonglong2 reads; pads compare false)
  if (tid < (int)ns){
    u64 key = selU[tid];
    u32 r = 0;
    #pragma unroll 8
    for (u32 j = 0; j < 1024; j += 2){
      ulonglong2 v = *reinterpret_cast<const ulonglong2*>(&selU[j]);
      r += (v.x < key) + (v.y < key);
    }
    keysL[r] = key;
  }
  // cand rank -> keep positions < R
  if (R > 0){
    for (u32 s = tid; s < nc; s += 1024){
      u64 key = candU[s];
      u32 r = 0;
      #pragma unroll 8
      for (u32 j = 0; j < nce; j += 2){
        ulonglong2 v = *reinterpret_cast<const ulonglong2*>(&candU[j]);
        r += (v.x < key) + (v.y < key);
      }
      if (r < (u32)R) keysL[ns + r] = key;
    }
  }
  __syncthreads();
  // decode (exactly the old k_decode arithmetic)
  if (tid < K){
    u64 key = keysL[tid];
    int g = b * KTOT + l * 1000 + tid;
    u32 idx = (u32)key;
    float o = funmap(~(u32)(key >> 32));
    int ai = c_LOFF[l] + (int)idx;
    const float* a = anchors + (size_t)ai * 4;
    const float* d = deltas + ((size_t)b * A_TOTAL + ai) * 4;
    float a0 = a[0], a1 = a[1], a2 = a[2], a3 = a[3];
    float wa = __fsub_rn(a2, a0), ha = __fsub_rn(a3, a1);
    float cxa = __fadd_rn(a0, __fmul_rn(0.5f, wa));
    float cya = __fadd_rn(a1, __fmul_rn(0.5f, ha));
    float dx = d[0], dy = d[1];
    float dw = fminf(d[2], 4.135166556742356f);   // log(1000/16)
    float dh = fminf(d[3], 4.135166556742356f);
    float cx = __fadd_rn(__fmul_rn(dx, wa), cxa);
    float cy = __fadd_rn(__fmul_rn(dy, ha), cya);
    float w  = __fmul_rn(expf(dw), wa);
    float h  = __fmul_rn(expf(dh), ha);
    float hw = __fmul_rn(0.5f, w), hh = __fmul_rn(0.5f, h);
    float x1 = __fsub_rn(cx, hw), y1 = __fsub_rn(cy, hh);
    float x2 = __fadd_rn(cx, hw), y2 = __fadd_rn(cy, hh);
    x1 = fminf(fmaxf(x1, 0.0f), 1216.0f);
    x2 = fminf(fmaxf(x2, 0.0f), 1216.0f);
    y1 = fminf(fmaxf(y1, 0.0f), 800.0f);
    y2 = fminf(fmaxf(y2, 0.0f), 800.0f);
    float s = __fdiv_rn(1.0f, __fadd_rn(1.0f, expf(-o)));
    int v = (__fsub_rn(x2, x1) >= 0.001f) && (__fsub_rn(y2, y1) >= 0.001f) && (s >= 0.0f);
    float* bo = boxes + (size_t)g * 4;
    bo[0] = x1; bo[1] = y1; bo[2] = x2; bo[3] = y2;
    scores[g] = s;
    valid[g] = (u32)v;
  }
}

// ---------- K3: suppression bitmask, 256-row x 64-col (one-word) slabs ----------
__global__ void __launch_bounds__(256)
k_mask(const float* __restrict__ boxes, u64* __restrict__ mask)
{
  int b = blockIdx.x / 184, s = blockIdx.x % 184;
  int l, idx;
  if (s < 160){ l = s / 40; idx = s % 40; }
  else        { l = 4;      idx = s - 160; }   // level 4: first 24 entries (w<=11)
  int w = c_MW[idx], rb = c_MR[idx];
  int N = c_LK[l];
  int koff = l * 1000;
  float offv = (float)(l * 4096);   // exact
  __shared__ float sjx1[64], sjy1[64], sjx2[64], sjy2[64], sjar[64];
  int jbase = w * 64;
  if (threadIdx.x < 64){
    int j = jbase + (int)threadIdx.x;
    float x1, y1, x2, y2, ar;
    if (j < N){
      float4 p = ((const float4*)boxes)[(size_t)(b * KTOT + koff + j)];
      x1 = __fadd_rn(p.x, offv); y1 = __fadd_rn(p.y, offv);
      x2 = __fadd_rn(p.z, offv); y2 = __fadd_rn(p.w, offv);
      ar = __fmul_rn(__fsub_rn(x2, x1), __fsub_rn(y2, y1));
    } else {
      x1 = 3e38f; y1 = 3e38f; x2 = -3e38f; y2 = -3e38f; ar = 0.f;
    }
    sjx1[threadIdx.x] = x1; sjy1[threadIdx.x] = y1;
    sjx2[threadIdx.x] = x2; sjy2[threadIdx.x] = y2; sjar[threadIdx.x] = ar;
  }
  __syncthreads();
  int i = rb * 256 + (int)threadIdx.x;
  int rows = (w + 1) * 64; if (rows > N) rows = N;
  if (i >= rows) return;
  float4 p = ((const float4*)boxes)[(size_t)(b * KTOT + koff + i)];
  float bx1 = __fadd_rn(p.x, offv), by1 = __fadd_rn(p.y, offv);
  float bx2 = __fadd_rn(p.z, offv), by2 = __fadd_rn(p.w, offv);
  float bar = __fmul_rn(__fsub_rn(bx2, bx1), __fsub_rn(by2, by1));
  u64 bw = 0;
  #pragma unroll 16
  for (int jj = 0; jj < 64; ++jj){
    int j = jbase + jj;
    float ltx = fmaxf(bx1, sjx1[jj]), lty = fmaxf(by1, sjy1[jj]);
    float rbx = fminf(bx2, sjx2[jj]), rby = fminf(by2, sjy2[jj]);
    float wx = fmaxf(__fsub_rn(rbx, ltx), 0.0f);
    float wy = fmaxf(__fsub_rn(rby, lty), 0.0f);
    float inter = __fmul_rn(wx, wy);
    bool sup = false;
    if (inter > 0.0f && j > i){
      float den = __fsub_rn(__fadd_rn(bar, sjar[jj]), inter);
      sup = __fdiv_rn(inter, den) > 0.7f;
    }
    bw |= ((u64)sup) << jj;
  }
  mask[((size_t)(b * 5 + l) * 16 + w) * 1024 + i] = bw;
}

// ---------- K4: exact greedy NMS + d_out zeroing (block bl zeroes its 1000 words) ----------
__global__ void __launch_bounds__(256)
k_nms(const u64* __restrict__ mask, const u32* __restrict__ valid,
      const float* __restrict__ scores, u64* __restrict__ outk,
      u64* __restrict__ keepw, float* __restrict__ outz)
{
  int bl = blockIdx.x; int b = bl / 5, l = bl % 5;
  int N = c_LK[l], koff = l * 1000;
  int WN = (N + 63) >> 6;           // 16 (levels 0-3) or 12 (level 4)
  int tid = threadIdx.x;
  // zero this block's 1000-float slice of d_out (40*1000 = 40000 = out_size);
  // completes before k_rank's scatter by dispatch ordering.
  for (int i = tid; i < 1000; i += 256) outz[bl * 1000 + i] = 0.0f;
  __shared__ u64 s_kw[16];
  __shared__ u64 s_m[7680];         // 60 KiB: word w at 64*w*(w+1)/2, rows <(w+1)*64
  const u64* mb = mask + (size_t)bl * 16 * 1024;
  int wstage = (WN < 15) ? WN : 15;
  for (int w = 0; w < wstage; ++w){
    int rows = (w + 1) * 64;
    int base = 32 * w * (w + 1);    // = 64*w*(w+1)/2
    for (int r = tid; r < rows; r += 256)
      s_m[base + r] = mb[(size_t)w * 1024 + r];
  }
  __syncthreads();
  if (tid < 64){
    int lane = tid;
    for (int c = 0; c < WN; ++c){
      int i = c * 64 + lane;
      int pred = (i < N) && (valid[(size_t)b * KTOT + koff + i] != 0u);
      u64 bal = __ballot(pred);
      if (lane == 0) s_kw[c] = bal;
    }
    for (int w = 0; w < WN; ++w){
      u64 kwv = s_kw[w];            // broadcast read (uniform)
      u64 supl = 0;
      if (w < 15){
        int base = 32 * w * (w + 1);
        for (int jb = 0; jb < w; ++jb){
          u64 kb = s_kw[jb];
          u64 m = s_m[base + jb * 64 + lane];            // unconditional ds_read
          supl |= (((kb >> lane) & 1ULL) ? m : 0ULL);
        }
      } else {
        for (int jb = 0; jb < w; ++jb){
          u64 kb = s_kw[jb];
          u64 m = mb[(size_t)w * 1024 + jb * 64 + lane]; // unconditional global
          supl |= (((kb >> lane) & 1ULL) ? m : 0ULL);
        }
      }
      int jr = w * 64 + lane;
      u64 rowl;
      if (w < 15) rowl = s_m[32 * w * (w + 1) + jr];     // diagonal rows staged
      else        rowl = (jr < N) ? mb[(size_t)w * 1024 + jr] : 0ULL;
      bool inC = ((kwv >> lane) & 1ULL) != 0ULL;
      u64 rkw = rowl & kwv;
      u64 confl = inC ? rkw : 0ULL;
      u32 a0 = (u32)supl, a1 = (u32)(supl >> 32);
      u32 a2 = (u32)confl, a3 = (u32)(confl >> 32);
      for (int off = 32; off; off >>= 1){
        a0 |= __shfl_xor(a0, off);
        a1 |= __shfl_xor(a1, off);
        a2 |= __shfl_xor(a2, off);
        a3 |= __shfl_xor(a3, off);
      }
      supl = ((u64)a1 << 32) | a0;
      u64 conf = ((u64)a3 << 32) | a2;          // union of in-word targets
      u64 srcb = __ballot(inC && (rkw != 0ULL)); // in-word source lanes
      u64 cur = kwv & ~supl;
      u64 kept = cur;
      if (((srcb & cur) != 0ULL) && ((conf & cur) != 0ULL)){
        u32 rowl_lo = (u32)rowl, rowl_hi = (u32)(rowl >> 32);
        u64 act = cur & (srcb | conf);
        while (act){
          int ib  = __ffsll((unsigned long long)act) - 1;  // wave-uniform
          int ibs = __builtin_amdgcn_readfirstlane(ib);
          u64 bit = 1ULL << ibs;
          act &= ~bit;
          if (kept & bit){
            u32 rlo = (u32)__builtin_amdgcn_readlane((int)rowl_lo, ibs);
            u32 rhi = (u32)__builtin_amdgcn_readlane((int)rowl_hi, ibs);
            u64 r   = ((u64)rhi << 32) | rlo;
            kept &= ~r;
            act  &= ~r;
          }
        }
      }
      if (lane == 0) s_kw[w] = kept;
    }
  }
  __syncthreads();
  if (tid < 16) keepw[(size_t)bl * 16 + tid] = (tid < WN) ? s_kw[tid] : 0ULL;
  for (int i = tid; i < N; i += 256){
    u64 key = ~0ULL;
    if ((s_kw[i >> 6] >> (i & 63)) & 1ULL){
      float sc = scores[(size_t)b * KTOT + koff + i];
      key = ((u64)(~fmap(sc)) << 32) | (u32)(koff + i);
    }
    outk[(size_t)b * KTOT + koff + i] = key;
  }
}

// ---------- K5: 5-way merge-rank final selection (O(K log K)) ----------
#define CMPN 1024   // per-level compacted list, padded with ~0ULL (kept count <= 1000)
__global__ void __launch_bounds__(256)
k_rank(const u64* __restrict__ outk, const u64* __restrict__ keepw,
       const float* __restrict__ boxes, float* __restrict__ out)
{
  int b = blockIdx.x / 19, chunk = blockIdx.x % 19;
  int tid = threadIdx.x;
  __shared__ u64 cmp[5 * CMPN];   // 40 KiB
  __shared__ u64 kw[80];          // keep words for this image's 5 levels
  for (int i = tid; i < 5 * CMPN; i += 256) cmp[i] = ~0ULL;
  if (tid < 80) kw[tid] = keepw[(size_t)b * 80 + tid];
  __syncthreads();
  for (int i = tid; i < KTOT; i += 256){
    u64 key = outk[(size_t)b * KTOT + i];
    if (key != ~0ULL){
      int l = i / 1000; if (l > 4) l = 4;
      int li = i - l * 1000;
      int wi = li >> 6, bit = li & 63;
      const u64* kwl = &kw[l * 16];
      int r = __popcll(kwl[wi] & ((1ULL << bit) - 1ULL));
      for (int w = 0; w < wi; ++w) r += __popcll(kwl[w]);
      cmp[l * CMPN + r] = key;
    }
  }
  __syncthreads();
  int i = chunk * 256 + tid;
  if (i >= KTOT) return;
  u64 key = outk[(size_t)b * KTOT + i];
  if (key == ~0ULL) return;     // suppressed / invalid
  int l = i / 1000; if (l > 4) l = 4;
  int li = i - l * 1000;
  int wi = li >> 6, bit = li & 63;
  const u64* kwl = &kw[l * 16];
  int rank = __popcll(kwl[wi] & ((1ULL << bit) - 1ULL));
  for (int w = 0; w < wi; ++w) rank += __popcll(kwl[w]);
  #pragma unroll
  for (int lo = 0; lo < 5; ++lo){
    if (lo == l) continue;
    int pos = 0;
    #pragma unroll
    for (int s = 512; s > 0; s >>= 1)
      if (cmp[lo * CMPN + pos + s - 1] < key) pos += s;
    rank += pos;   // count of kept keys in level lo that are < key
  }
  if (rank < 1000){
    float4 bx = ((const float4*)boxes)[(size_t)(b * KTOT + i)];
    ((float4*)out)[(size_t)(b * 1000 + rank)] = bx;
    out[32000 + b * 1000 + rank] = funmap(~(u32)(key >> 32));
  }
}

extern "C" void kernel_launch(void* const* d_in, const int* in_sizes, int n_in,
                              void* d_out, int out_size, void* d_ws, size_t ws_size,
                              hipStream_t stream)
{
  (void)in_sizes; (void)n_in; (void)out_size; (void)ws_size; // needs ~8.73 MB ws
  const float* obj     = (const float*)d_in[0];
  const float* deltas  = (const float*)d_in[1];
  const float* anchors = (const float*)d_in[2];
  float* out = (float*)d_out;
  char* ws = (char*)d_ws;

  u32* hist    = (u32*)(ws + OFF_HIST);
  u64* keepw   = (u64*)(ws + OFF_KEEPW);   // aliases hist (dead by k_nms time)
  u32* selcnt  = (u32*)(ws + OFF_SELCNT);
  u32* candcnt = (u32*)(ws + OFF_CANDCNT);
  u64* selg    = (u64*)(ws + OFF_SELG);
  u64* candg   = (u64*)(ws + OFF_CANDG);
  float* boxes = (float*)(ws + OFF_BOX);
  float* score = (float*)(ws + OFF_SCORE);
  u32* valid   = (u32*)(ws + OFF_VALID);
  u64* mask    = (u64*)(ws + OFF_MASK);
  u64* outk    = (u64*)(ws + OFF_OUTK);

  hipLaunchKernelGGL(k_zero,      dim3((ZWS + 255) / 256), dim3(256), 0, stream, (u32*)ws);
  hipLaunchKernelGGL(k_hist,      dim3(264),  dim3(1024), 0, stream, obj, hist);
  hipLaunchKernelGGL(k_collect,   dim3(264),  dim3(1024), 0, stream, obj, hist, selcnt, candcnt, selg, candg);
  hipLaunchKernelGGL(k_selectdec, dim3(40),   dim3(1024), 0, stream, selcnt, candcnt, selg, candg,
                     deltas, anchors, boxes, score, valid);
  hipLaunchKernelGGL(k_mask,      dim3(1472), dim3(256),  0, stream, boxes, mask);
  hipLaunchKernelGGL(k_nms,       dim3(40),   dim3(256),  0, stream, mask, valid, score, outk, keepw, out);
  hipLaunchKernelGGL(k_rank,      dim3(152),  dim3(256),  0, stream, outk, keepw, boxes, out);
}